// Round 9
// baseline (160.616 us; speedup 1.0000x reference)
//
#include <hip/hip_runtime.h>
#include <hip/hip_bf16.h>
#include <stdint.h>
#include <stddef.h>

// ---------------------------------------------------------------------------
// InteractionPredictionHead: edge MLP.
// feats@W1 = P[src] + Q[dst] + attr@W1c + b1  (P,Q per-node, 50k not 300k).
// R9:
//  - fused: 16 edges/wave, ALL weights (W2/W3/W4/w1c) read from global
//    k-major images (L1-broadcast: every wave reads the same lines) ->
//    LDS pipe demand drops ~60% (R8 diagnosis: LDS pipe 28us was top pipe),
//    ZERO barriers (per-wave h2/h3 slots only: 6.6KB/wave).
//  - acc2 = 8 x f32x4 = 32 AGPR; freed regs fund 4-deep gather lookahead
//    (8 named p/q bufs). VGPR+AGPR target <= 128 (occupancy class: steps at
//    64/128/256 total regs — calibrated on R5/R7/R8).
//  - gemm1: 2 node-tiles per block (rep loop) -> weight preload halved.
// Layers 2-4: mfma_f32_16x16x32_bf16; gemm1: 32x32x16.
// ---------------------------------------------------------------------------

#define NN 50000
#define NE 300000
#define KG(kq,g2) ((kq)*2+(g2))

using bf16x8 = __attribute__((ext_vector_type(8))) short;
using f32x16 = __attribute__((ext_vector_type(16))) float;
using f32x4  = __attribute__((ext_vector_type(4))) float;
using f32x2  = __attribute__((ext_vector_type(2))) float;
using u32x4  = __attribute__((ext_vector_type(4))) unsigned int;
using u32x2  = __attribute__((ext_vector_type(2))) unsigned int;

// ---- ws layout (bytes, 16B aligned) ----
#define OFF_PQ   0ULL
#define SZ_PQ    (50000ULL*512ULL*2ULL)          // PQ bf16 [n][512]
#define OFF_W1   (OFF_PQ + SZ_PQ)                // W1 img (32-style) [kg32][512][8]
#define SZ_W1    (512ULL*256ULL*2ULL)
#define OFF_W1C  (OFF_W1 + SZ_W1)                // W1c f32 [3][256]
#define SZ_W1C   (3ULL*256ULL*4ULL)
#define OFF_W2   (OFF_W1C + SZ_W1C)              // W2 img (16-style) [sg32][128][8]
#define SZ_W2    (128ULL*256ULL*2ULL)
#define OFF_W3   (OFF_W2 + SZ_W2)                // W3 img (16-style) [sg16][64][8]
#define SZ_W3    (64ULL*128ULL*2ULL)
#define OFF_W4   (OFF_W3 + SZ_W3)                // W4 img (16-style) [sg8][16][8]
#define SZ_W4    (16ULL*64ULL*2ULL)
#define OFF_FLAG (OFF_W4 + SZ_W4)
#define WS_NEED  (OFF_FLAG + 16ULL)

__device__ __forceinline__ unsigned short f2bf(float x){
  unsigned u = __float_as_uint(x);
  unsigned r = 0x7FFFu + ((u >> 16) & 1u);
  return (unsigned short)((u + r) >> 16);
}
__device__ __forceinline__ unsigned cvtpk(float lo, float hi){
  unsigned r;
  asm("v_cvt_pk_bf16_f32 %0, %1, %2" : "=v"(r) : "v"(lo), "v"(hi));
  return r;
}
__device__ __forceinline__ f32x2 unpk(unsigned w){
  f32x2 r;
  r[0] = __uint_as_float(w << 16);
  r[1] = __uint_as_float(w & 0xFFFF0000u);
  return r;
}
__device__ __forceinline__ f32x16 mfma32(bf16x8 a, bf16x8 b, f32x16 c){
  return __builtin_amdgcn_mfma_f32_32x32x16_bf16(a, b, c, 0, 0, 0);
}
__device__ __forceinline__ f32x4 mfma16(bf16x8 a, bf16x8 b, f32x4 c){
  return __builtin_amdgcn_mfma_f32_16x16x32_bf16(a, b, c, 0, 0, 0);
}
__device__ __forceinline__ f32x16 zero16(){
  f32x16 v;
#pragma unroll
  for (int i = 0; i < 16; ++i) v[i] = 0.f;
  return v;
}

// ---------------------------------------------------------------------------
// prep_pack: weight images + int64 flag (identical to R8).
// ---------------------------------------------------------------------------
__global__ void prep_pack(const float* __restrict__ W1, const float* __restrict__ W2,
                          const float* __restrict__ W3, const float* __restrict__ W4,
                          const int* __restrict__ ei32, char* __restrict__ ws)
{
  int i = blockIdx.x * 256 + threadIdx.x;
  unsigned short* w1i = (unsigned short*)(ws + OFF_W1);
  unsigned short* w2i = (unsigned short*)(ws + OFF_W2);
  unsigned short* w3i = (unsigned short*)(ws + OFF_W3);
  unsigned short* w4i = (unsigned short*)(ws + OFF_W4);

  if (i < 131072){
    int j = i & 7, out = (i >> 3) & 511, kg = i >> 12;
    int k = (kg >> 1)*16 + (kg & 1)*8 + j;
    float v = (out < 256) ? W1[(size_t)k*256 + out]
                          : W1[(size_t)(256 + k)*256 + (out - 256)];
    w1i[i] = f2bf(v);
  } else if (i < 131072 + 32768){
    int i2 = i - 131072;
    int j = i2 & 7, out = (i2 >> 3) & 127, sg = i2 >> 10;
    int k = (sg >> 2)*32 + (sg & 3)*8 + j;
    w2i[i2] = f2bf(W2[(size_t)k*128 + out]);
  } else if (i < 131072 + 32768 + 8192){
    int i3 = i - 131072 - 32768;
    int j = i3 & 7, out = (i3 >> 3) & 63, sg = i3 >> 9;
    int k = (sg >> 2)*32 + (sg & 3)*8 + j;
    w3i[i3] = f2bf(W3[(size_t)k*64 + out]);
  } else if (i < 131072 + 32768 + 8192 + 1024){
    int i4 = i - 131072 - 32768 - 8192;
    int j = i4 & 7, out = (i4 >> 3) & 15, sg = i4 >> 7;
    int k = (sg >> 2)*32 + (sg & 3)*8 + j;
    w4i[i4] = (out < 3) ? f2bf(W4[(size_t)k*3 + out]) : (unsigned short)0;
  }
  if (i < 768){
    float* w1c = (float*)(ws + OFF_W1C);
    w1c[i] = W1[(size_t)(512 + i/256)*256 + (i & 255)];
  }
  if (i == 0){
    int f = 1;
    for (int t = 1; t < 64; t += 2) if (ei32[t] != 0) { f = 0; break; }
    *(int*)(ws + OFF_FLAG) = f;
  }
}

// ---------------------------------------------------------------------------
// gemm1: PQ = emb @ W1ab (+b1). 8 waves x 64 outs reg-stationary; 2 node-tiles
// of 64 per block (rep loop amortizes the 32KB/wave weight preload).
// ---------------------------------------------------------------------------
__global__ __launch_bounds__(512, 2) void gemm1(const float* __restrict__ emb,
                                                const float* __restrict__ b1,
                                                char* __restrict__ ws)
{
  // union: emb staging [kg][node][8] (32KB); epilogue [32 rows][516 shorts]
  __shared__ __align__(16) unsigned short U[16896];   // 33792 B

  const int tid = threadIdx.x;
  const int wv = tid >> 6, l = tid & 63, ln = l & 31, g2 = l >> 5;
  const int ob = wv * 64;
  const unsigned short* w1L = (const unsigned short*)(ws + OFF_W1);
  unsigned short* PQ = (unsigned short*)(ws + OFF_PQ);

  // reg-stationary weights: 2 tiles x 16 kq = 128 VGPR, loaded ONCE per block
  bf16x8 aw[2][16];
#pragma unroll
  for (int kq = 0; kq < 16; ++kq){
#pragma unroll
    for (int t2 = 0; t2 < 2; ++t2)
      aw[t2][kq] = *(const bf16x8*)(w1L + ((size_t)KG(kq,g2)*512 + ob + t2*32 + ln)*8);
  }

#pragma unroll 1
  for (int rep = 0; rep < 2; ++rep){
    const int nb = (blockIdx.x*2 + rep) * 64;
    __syncthreads();   // previous rep's epilogue reads of U done

    // stage emb tile -> LDS bf16 k-major
#pragma unroll
    for (int it = 0; it < 8; ++it){
      int u = it*512 + tid;                      // 0..4095
      int kg = u >> 7, node = (u >> 1) & 63, half = u & 1;
      int n = nb + node; if (n >= NN) n = NN - 1;
      int k = (kg >> 1)*16 + (kg & 1)*8 + half*4;
      f32x4 e = *(const f32x4*)(emb + (size_t)n*256 + k);
      u32x2 w; w[0] = cvtpk(e[0], e[1]); w[1] = cvtpk(e[2], e[3]);
      *(u32x2*)(U + (size_t)kg*512 + node*8 + half*4) = w;
    }
    __syncthreads();

    f32x16 acc[2][2];
    acc[0][0] = zero16(); acc[0][1] = zero16();
    acc[1][0] = zero16(); acc[1][1] = zero16();
#pragma unroll
    for (int kq = 0; kq < 16; ++kq){
      bf16x8 b0  = *(const bf16x8*)(U + ((size_t)KG(kq,g2)*64 +      ln)*8);
      bf16x8 b1v = *(const bf16x8*)(U + ((size_t)KG(kq,g2)*64 + 32 + ln)*8);
      acc[0][0] = mfma32(aw[0][kq], b0,  acc[0][0]);
      acc[1][0] = mfma32(aw[1][kq], b0,  acc[1][0]);
      acc[0][1] = mfma32(aw[0][kq], b1v, acc[0][1]);
      acc[1][1] = mfma32(aw[1][kq], b1v, acc[1][1]);
    }
    __syncthreads();   // done reading emb staging; U becomes transpose buffer

    // epilogue: 2 passes of 32 nodes through padded LDS [32][516]
    const int r_ = tid >> 4;          // 0..31 (store row)
    const int j_ = tid & 15;          // 0..15 (store chunk)
#define G1PASS(BG)                                                             \
    {                                                                          \
      _Pragma("unroll")                                                        \
      for (int t2 = 0; t2 < 2; ++t2){                                          \
        _Pragma("unroll")                                                      \
        for (int rr = 0; rr < 4; ++rr){                                        \
          int o = ob + t2*32 + rr*8 + g2*4;                                    \
          f32x4 bv = {0.f,0.f,0.f,0.f};                                        \
          if (ob + t2*32 < 256) bv = *(const f32x4*)(b1 + o);                  \
          unsigned d0 = cvtpk(acc[t2][BG][rr*4+0]+bv[0], acc[t2][BG][rr*4+1]+bv[1]); \
          unsigned d1 = cvtpk(acc[t2][BG][rr*4+2]+bv[2], acc[t2][BG][rr*4+3]+bv[3]); \
          u32x2 st = {d0, d1};                                                 \
          *(u32x2*)(U + (size_t)ln*516 + o) = st;                              \
        }                                                                      \
      }                                                                        \
      __syncthreads();                                                         \
      {                                                                        \
        int n = nb + (BG)*32 + r_;                                             \
        if (n < NN){                                                           \
          _Pragma("unroll")                                                    \
          for (int ii = 0; ii < 4; ++ii){                                      \
            uint4 v = *(const uint4*)(U + (size_t)r_*516 + ii*128 + j_*8);     \
            *(uint4*)(PQ + (size_t)n*512 + ii*128 + j_*8) = v;                 \
          }                                                                    \
        }                                                                      \
      }                                                                        \
    }
    G1PASS(0);
    __syncthreads();
    G1PASS(1);
#undef G1PASS
  }
}

// ---------------------------------------------------------------------------
// fused: 256 thr (4 waves), 16 edges/wave, 16x16x32 MFMA, ZERO barriers.
// Weights from global k-major images (L1-broadcast); per-wave LDS slots:
// h2 [16][136] (4352B) + h3 [16][72] (2304B) = 6656B/wave, 26624B/block.
// Gathers: 4-deep lookahead, 8 named p/q bufs (32 VGPR).
// ---------------------------------------------------------------------------

#define PAIRX(LO, HI, D) ((D)==0 ? (f32x2){(LO)[0],(LO)[1]} : \
                          (D)==1 ? (f32x2){(LO)[2],(LO)[3]} : \
                          (D)==2 ? (f32x2){(HI)[0],(HI)[1]} : \
                                   (f32x2){(HI)[2],(HI)[3]})

// one K=32 step: w1c slice from global (L1), build h1 B-frag from preloaded
// P/Q, reload P/Q for step S+4, 8 A-frags from global W2 image (L1), 8 MFMA.
#define L2G(S, PC, QC)                                                         \
  {                                                                            \
    const int kb = (S)*32 + g4*8;                                              \
    f32x4 w0lo = *(const f32x4*)(w1cg +   0 + kb);                             \
    f32x4 w0hi = *(const f32x4*)(w1cg +   4 + kb);                             \
    f32x4 w1lo = *(const f32x4*)(w1cg + 256 + kb);                             \
    f32x4 w1hi = *(const f32x4*)(w1cg + 260 + kb);                             \
    f32x4 w2lo = *(const f32x4*)(w1cg + 512 + kb);                             \
    f32x4 w2hi = *(const f32x4*)(w1cg + 516 + kb);                             \
    u32x4 pu = __builtin_bit_cast(u32x4, PC);                                  \
    u32x4 qu = __builtin_bit_cast(u32x4, QC);                                  \
    f32x2 z2 = {0.f, 0.f};                                                     \
    unsigned bu0, bu1, bu2, bu3;                                               \
    _Pragma("unroll")                                                          \
    for (int d = 0; d < 4; ++d){                                               \
      f32x2 h = unpk(pu[d]) + unpk(qu[d]);                                     \
      h += PAIRX(w0lo, w0hi, d) * at0;                                         \
      h += PAIRX(w1lo, w1hi, d) * at1;                                         \
      h += PAIRX(w2lo, w2hi, d) * at2;                                         \
      h = __builtin_elementwise_max(h, z2);                                    \
      unsigned c = cvtpk(h[0], h[1]);                                          \
      if (d==0) bu0 = c; else if (d==1) bu1 = c; else if (d==2) bu2 = c;       \
      else bu3 = c;                                                            \
    }                                                                          \
    u32x4 buv = {bu0, bu1, bu2, bu3};                                          \
    bf16x8 b = __builtin_bit_cast(bf16x8, buv);                                \
    if ((S) + 4 <= 7){                                                         \
      PC = *(const bf16x8*)(Prow + ((S)+4)*32);                                \
      QC = *(const bf16x8*)(Qrow + ((S)+4)*32);                                \
    }                                                                          \
    const unsigned short* ab = w2g + ((size_t)((S)*4 + g4)*128 + c16)*8;       \
    _Pragma("unroll")                                                          \
    for (int t = 0; t < 8; ++t){                                               \
      bf16x8 af = *(const bf16x8*)(ab + t*128);                                \
      acc2[t] = mfma16(af, b, acc2[t]);                                        \
    }                                                                          \
  }

__global__ __launch_bounds__(256, 4) void fused(const int* __restrict__ eidx,
                                                const float* __restrict__ attr,
                                                const float* __restrict__ b2,
                                                const float* __restrict__ b3,
                                                const float* __restrict__ b4,
                                                const char* __restrict__ ws,
                                                float* __restrict__ out)
{
  __shared__ __align__(16) unsigned short h2s[4][16*136];  // 4352 B/wave
  __shared__ __align__(16) unsigned short h3s[4][16*72];   // 2304 B/wave

  const int tid = threadIdx.x;
  const int wv = tid >> 6, l = tid & 63, c16 = l & 15, g4 = l >> 4;
  unsigned short* h2w = h2s[wv];
  unsigned short* h3w = h3s[wv];

  const unsigned short* PQ  = (const unsigned short*)(ws + OFF_PQ);
  const unsigned short* w2g = (const unsigned short*)(ws + OFF_W2);
  const unsigned short* w3g = (const unsigned short*)(ws + OFF_W3);
  const unsigned short* w4g = (const unsigned short*)(ws + OFF_W4);
  const float* w1cg = (const float*)(ws + OFF_W1C);
  const int flag64 = *(const int*)(ws + OFF_FLAG);

  const int e = blockIdx.x * 64 + wv * 16 + c16;
  const bool ev = (e < NE);
  const int ec = ev ? e : 0;
  const int si = flag64 ? eidx[2*(size_t)ec]        : eidx[ec];
  const int di = flag64 ? eidx[2*((size_t)NE + ec)] : eidx[NE + ec];
  const float at0 = ev ? attr[(size_t)ec*3 + 0] : 0.f;
  const float at1 = ev ? attr[(size_t)ec*3 + 1] : 0.f;
  const float at2 = ev ? attr[(size_t)ec*3 + 2] : 0.f;

  const unsigned short* Prow = PQ + (size_t)si*512 + g4*8;
  const unsigned short* Qrow = PQ + (size_t)di*512 + 256 + g4*8;

  // prime 4-deep gather pipeline (8 loads in flight per thread)
  bf16x8 pA = *(const bf16x8*)(Prow +  0), qA = *(const bf16x8*)(Qrow +  0);
  bf16x8 pB = *(const bf16x8*)(Prow + 32), qB = *(const bf16x8*)(Qrow + 32);
  bf16x8 pC = *(const bf16x8*)(Prow + 64), qC = *(const bf16x8*)(Qrow + 64);
  bf16x8 pD = *(const bf16x8*)(Prow + 96), qD = *(const bf16x8*)(Qrow + 96);

  // ---------------- Layer 2: K=256 (8 steps), 128 outs ---------------------
  f32x4 acc2[8];
#pragma unroll
  for (int t = 0; t < 8; ++t) acc2[t] = (f32x4){0.f,0.f,0.f,0.f};

  L2G(0, pA, qA);
  L2G(1, pB, qB);
  L2G(2, pC, qC);
  L2G(3, pD, qD);
  L2G(4, pA, qA);
  L2G(5, pB, qB);
  L2G(6, pC, qC);
  L2G(7, pD, qD);

  // h2 -> per-wave slot [16 e][136] (+b2, bf16). Same-wave LDS RAW in-order.
#pragma unroll
  for (int t = 0; t < 8; ++t){
    f32x4 bv = *(const f32x4*)(b2 + t*16 + g4*4);
    unsigned d0 = cvtpk(acc2[t][0]+bv[0], acc2[t][1]+bv[1]);
    unsigned d1 = cvtpk(acc2[t][2]+bv[2], acc2[t][3]+bv[3]);
    u32x2 st = {d0, d1};
    *(u32x2*)(h2w + (size_t)c16*136 + t*16 + g4*4) = st;
  }

  // ---------------- Layer 3: K=128 (4 steps), 64 outs ----------------------
  f32x4 acc3[4];
#pragma unroll
  for (int t = 0; t < 4; ++t) acc3[t] = (f32x4){0.f,0.f,0.f,0.f};
#pragma unroll
  for (int ks = 0; ks < 4; ++ks){
    bf16x8 bb = *(const bf16x8*)(h2w + (size_t)c16*136 + ks*32 + g4*8);
    const unsigned short* ab3 = w3g + ((size_t)(ks*4 + g4)*64 + c16)*8;
#pragma unroll
    for (int t = 0; t < 4; ++t){
      bf16x8 af = *(const bf16x8*)(ab3 + t*128);
      acc3[t] = mfma16(af, bb, acc3[t]);
    }
  }

  // h3 -> per-wave slot [16 e][72] (relu, +b3)
#pragma unroll
  for (int t = 0; t < 4; ++t){
    f32x4 bv = *(const f32x4*)(b3 + t*16 + g4*4);
    unsigned d0 = cvtpk(fmaxf(acc3[t][0]+bv[0],0.f), fmaxf(acc3[t][1]+bv[1],0.f));
    unsigned d1 = cvtpk(fmaxf(acc3[t][2]+bv[2],0.f), fmaxf(acc3[t][3]+bv[3],0.f));
    u32x2 st = {d0, d1};
    *(u32x2*)(h3w + (size_t)c16*72 + t*16 + g4*4) = st;
  }

  // ---------------- Layer 4: K=64 (2 steps), 3 outs ------------------------
  f32x4 acc4 = {0.f,0.f,0.f,0.f};
#pragma unroll
  for (int ks = 0; ks < 2; ++ks){
    bf16x8 af = *(const bf16x8*)(w4g + ((size_t)(ks*4 + g4)*16 + c16)*8);
    bf16x8 bb = *(const bf16x8*)(h3w + (size_t)c16*72 + ks*32 + g4*8);
    acc4 = mfma16(af, bb, acc4);
  }
  if (g4 == 0 && ev){
    out[(size_t)e*3 + 0] = acc4[0] + b4[0];
    out[(size_t)e*3 + 1] = acc4[1] + b4[1];
    out[(size_t)e*3 + 2] = acc4[2] + b4[2];
  }
}

// ---------------------------------------------------------------------------
extern "C" void kernel_launch(void* const* d_in, const int* in_sizes, int n_in,
                              void* d_out, int out_size, void* d_ws, size_t ws_size,
                              hipStream_t stream)
{
  const float* emb  = (const float*)d_in[0];
  const int*   eidx = (const int*)  d_in[1];
  const float* attr = (const float*)d_in[2];
  const float* W1   = (const float*)d_in[3];
  const float* b1   = (const float*)d_in[4];
  const float* W2   = (const float*)d_in[5];
  const float* b2   = (const float*)d_in[6];
  const float* W3   = (const float*)d_in[7];
  const float* b3   = (const float*)d_in[8];
  const float* W4   = (const float*)d_in[9];
  const float* b4   = (const float*)d_in[10];
  char* ws = (char*)d_ws;
  float* out = (float*)d_out;

  if (ws_size < WS_NEED) return;

  prep_pack<<<676, 256, 0, stream>>>(W1, W2, W3, W4, eidx, ws);
  gemm1<<<(NN + 127)/128, 512, 0, stream>>>(emb, b1, ws);
  fused<<<(NE + 63)/64, 256, 0, stream>>>(eidx, attr, b2, b3, b4, ws, out);
}